// Round 1
// baseline (2842.137 us; speedup 1.0000x reference)
//
#include <hip/hip_runtime.h>
#include <math.h>

// Problem constants
#define B_ 256
#define T_ 2000
#define I_ 80
#define H_ 20
#define G_ 80      // 4*H
#define M_ 512000  // B*T

__device__ __forceinline__ float sigmoid_f(float x) {
    return 1.0f / (1.0f + __expf(-x));
}
__device__ __forceinline__ float tanh_f(float x) {
    // 1 - 2/(exp(2x)+1): exactly saturating at +-1 for large |x|
    return 1.0f - 2.0f / (__expf(2.0f * x) + 1.0f);
}

// ---------------------------------------------------------------------------
// GEMM: XG[row][d*80+g] = sum_k X[row][k] * Wih[d][k][g] + Bias[d][g]
// rows = B*T, K = 80 (layer0) or 40 (layer1), N = 160 (both dirs)
// tile: 96 rows x 160 cols, 8x8 micro-tile, K staged in chunks of 40.
// ---------------------------------------------------------------------------
template<int K>
__global__ __launch_bounds__(256) void gemm_xg(
    const float* __restrict__ X,     // (M, K)
    const float* __restrict__ Wih,   // (2, K, 80)
    const float* __restrict__ Bias,  // (2, 80)
    float* __restrict__ XG,          // (M, 160)
    int M)
{
    constexpr int KC = 40;
    __shared__ float ws[KC][164];   // [k][col], pad 160->164 (16B-aligned rows)
    __shared__ float xs[KC][100];   // [k][row], pad 96->100 (16B-aligned rows)
    __shared__ float bs[160];

    const int tid  = threadIdx.x;
    const int row0 = blockIdx.x * 96;
    const int tx = tid % 20;        // col group: cols 8*tx .. 8*tx+7
    const int ty = tid / 20;        // row group: rows 8*ty .. 8*ty+7 (ty<12 active)
    const bool run = (ty < 12);

    if (tid < 160) {
        int d = (tid >= 80);
        bs[tid] = Bias[d * 80 + (tid - 80 * d)];
    }

    int nrows = M - row0; if (nrows > 96) nrows = 96;

    float acc[8][8];
    bool first = true;

    for (int kc = 0; kc < K; kc += KC) {
        // stage weights chunk: ws[i][c] = Wih[d][kc+i][g], c = d*80+g
        for (int idx = tid; idx < KC * 160; idx += 256) {
            int i = idx / 160, c = idx - 160 * i;
            int d = (c >= 80), g = c - 80 * d;
            ws[i][c] = Wih[(d * K + kc + i) * 80 + g];
        }
        // stage x chunk, transposed: xs[k][r] = X[row0+r][kc+k]
        for (int i4 = tid; i4 < (96 * KC) / 4; i4 += 256) {
            int r = i4 / 10;
            int kk = (i4 - 10 * r) * 4;
            float4 v = make_float4(0.f, 0.f, 0.f, 0.f);
            if (r < nrows)
                v = *(const float4*)(X + (long long)(row0 + r) * K + kc + kk);
            xs[kk][r] = v.x; xs[kk + 1][r] = v.y; xs[kk + 2][r] = v.z; xs[kk + 3][r] = v.w;
        }
        __syncthreads();

        if (first) {
            first = false;
            float bv[8];
            #pragma unroll
            for (int cc = 0; cc < 8; ++cc) bv[cc] = bs[tx * 8 + cc];
            #pragma unroll
            for (int r = 0; r < 8; ++r)
                #pragma unroll
                for (int cc = 0; cc < 8; ++cc) acc[r][cc] = bv[cc];
        }

        if (run) {
            #pragma unroll 4
            for (int k = 0; k < KC; ++k) {
                float a[8], bb[8];
                *(float4*)&a[0]  = *(const float4*)&xs[k][ty * 8];
                *(float4*)&a[4]  = *(const float4*)&xs[k][ty * 8 + 4];
                *(float4*)&bb[0] = *(const float4*)&ws[k][tx * 8];
                *(float4*)&bb[4] = *(const float4*)&ws[k][tx * 8 + 4];
                #pragma unroll
                for (int r = 0; r < 8; ++r)
                    #pragma unroll
                    for (int cc = 0; cc < 8; ++cc)
                        acc[r][cc] = fmaf(a[r], bb[cc], acc[r][cc]);
            }
        }
        __syncthreads();
    }

    if (run) {
        #pragma unroll
        for (int r = 0; r < 8; ++r) {
            int row = row0 + ty * 8 + r;
            if (row < M) {
                float* dst = XG + (long long)row * 160 + tx * 8;
                *(float4*)(dst)     = *(float4*)&acc[r][0];
                *(float4*)(dst + 4) = *(float4*)&acc[r][4];
            }
        }
    }
}

// ---------------------------------------------------------------------------
// LSTM scan: one wave (64 lanes) per block; lanes 0-31 = forward dir of batch
// b, lanes 32-63 = backward dir of batch b. Within a half, lane j (j<20) owns
// hidden unit j: holds c_j and all recurrent weights for gates {i,f,g,o}_j.
// h (20 floats) is replicated across lanes of the half, rebuilt per step with
// width-32 shuffles. xg loads are software-pipelined 4 steps deep.
// ---------------------------------------------------------------------------
__global__ __launch_bounds__(64) void lstm_scan(
    const float* __restrict__ xg,    // (B, T, 2, 80): row = ((b*T+t)*2+d)*80
    const float* __restrict__ w_hh,  // (2, 20, 80)
    float* __restrict__ h_out,       // (B, T, 40): [b][t][d*20+j]
    int T)
{
    const int b    = blockIdx.x;          // 0..255
    const int lane = threadIdx.x;         // 0..63
    const int d    = lane >> 5;           // 0 = fwd, 1 = bwd
    const int j    = lane & 31;
    const bool act = (j < H_);
    const int jj   = act ? j : 0;         // clamp for safe addressing

    // Recurrent weights: wr[g][k] = w_hh[d][k][g*20 + jj]
    float wr[4][20];
    const float* wbase = w_hh + d * (H_ * G_);
    #pragma unroll
    for (int k = 0; k < 20; ++k) {
        #pragma unroll
        for (int g = 0; g < 4; ++g)
            wr[g][k] = wbase[k * G_ + g * 20 + jj];
    }

    float h[20];
    #pragma unroll
    for (int k = 0; k < 20; ++k) h[k] = 0.f;
    float c = 0.f;

    const int t0 = d ? (T - 1) : 0;
    const float* row = xg + ((long long)(b * T + t0) * 2 + d) * 80;
    const int rstep = d ? -160 : 160;

    float* hout = h_out + (long long)(b * T + t0) * 40 + d * 20 + j;
    const int hstep = d ? -40 : 40;

    // 4-deep prefetch pipeline
    float px[4][4];
    #pragma unroll
    for (int s = 0; s < 4; ++s) {
        const float* r = row + (long long)s * rstep;
        px[s][0] = r[jj]; px[s][1] = r[20 + jj]; px[s][2] = r[40 + jj]; px[s][3] = r[60 + jj];
    }

    for (int tb = 0; tb < T; tb += 4) {
        #pragma unroll
        for (int s = 0; s < 4; ++s) {
            const int t = tb + s;
            const float xi = px[s][0], xf = px[s][1], xgv = px[s][2], xo = px[s][3];

            // prefetch t+4 into the slot we just consumed
            if (t + 4 < T) {
                const float* r = row + (long long)(t + 4) * rstep;
                px[s][0] = r[jj]; px[s][1] = r[20 + jj]; px[s][2] = r[40 + jj]; px[s][3] = r[60 + jj];
            }

            // gates: split accumulators (2 chains per gate) for shorter dep chains
            float ai0 = xi, ai1 = 0.f, af0 = xf, af1 = 0.f;
            float ag0 = xgv, ag1 = 0.f, ao0 = xo, ao1 = 0.f;
            #pragma unroll
            for (int k = 0; k < 20; k += 2) {
                ai0 = fmaf(h[k],     wr[0][k],     ai0);
                ai1 = fmaf(h[k + 1], wr[0][k + 1], ai1);
                af0 = fmaf(h[k],     wr[1][k],     af0);
                af1 = fmaf(h[k + 1], wr[1][k + 1], af1);
                ag0 = fmaf(h[k],     wr[2][k],     ag0);
                ag1 = fmaf(h[k + 1], wr[2][k + 1], ag1);
                ao0 = fmaf(h[k],     wr[3][k],     ao0);
                ao1 = fmaf(h[k + 1], wr[3][k + 1], ao1);
            }
            const float gi = sigmoid_f(ai0 + ai1);
            const float gf = sigmoid_f(af0 + af1);
            const float gg = tanh_f(ag0 + ag1);
            const float go = sigmoid_f(ao0 + ao1);

            c = fmaf(gf, c, gi * gg);
            const float hj = go * tanh_f(c);

            if (act) *hout = hj;
            hout += hstep;

            // rebuild replicated h via width-32 broadcasts
            #pragma unroll
            for (int k = 0; k < 20; ++k) h[k] = __shfl(hj, k, 32);
        }
    }
}

// ---------------------------------------------------------------------------
// FC: out[row] = dot(h1[row][0:40], fc_w) + fc_b.  256 rows per block,
// LDS-staged with pad-41 rows (bank-conflict-free: 41*tid mod 32 hits all banks)
// ---------------------------------------------------------------------------
__global__ __launch_bounds__(256) void fc_kernel(
    const float* __restrict__ H1,   // (M, 40)
    const float* __restrict__ Wf,   // (40,)
    const float* __restrict__ Bf,   // (1,)
    float* __restrict__ Out)        // (M,)
{
    __shared__ float ls[256 * 41];
    __shared__ float wl[40];
    const int tid = threadIdx.x;
    const long long row0 = (long long)blockIdx.x * 256;
    const float* src = H1 + row0 * 40;

    #pragma unroll
    for (int it = 0; it < 10; ++it) {
        int i4 = tid + it * 256;            // 0..2559
        float4 v = *(const float4*)(src + (long long)i4 * 4);
        int flat = i4 * 4;
        int r = flat / 40, jc = flat - 40 * r;  // 40%4==0: never straddles rows
        float* dp = &ls[r * 41 + jc];
        dp[0] = v.x; dp[1] = v.y; dp[2] = v.z; dp[3] = v.w;
    }
    if (tid < 40) wl[tid] = Wf[tid];
    __syncthreads();

    float acc = Bf[0];
    #pragma unroll
    for (int jc = 0; jc < 40; ++jc)
        acc = fmaf(ls[tid * 41 + jc], wl[jc], acc);
    Out[row0 + tid] = acc;
}

// ---------------------------------------------------------------------------
extern "C" void kernel_launch(void* const* d_in, const int* in_sizes, int n_in,
                              void* d_out, int out_size, void* d_ws, size_t ws_size,
                              hipStream_t stream) {
    const float* x     = (const float*)d_in[0];
    const float* wih0  = (const float*)d_in[1];
    const float* whh0  = (const float*)d_in[2];
    const float* b0    = (const float*)d_in[3];
    const float* wih1  = (const float*)d_in[4];
    const float* whh1  = (const float*)d_in[5];
    const float* b1    = (const float*)d_in[6];
    const float* fcw   = (const float*)d_in[7];
    const float* fcb   = (const float*)d_in[8];
    float* out = (float*)d_out;

    float* ws = (float*)d_ws;
    float* xg = ws;                        // B*T*2*80 = 81,920,000 floats
    float* h0 = ws + 81920000LL;           // B*T*40   = 20,480,000 floats
    float* h1 = ws + 102400000LL;          // B*T*40   = 20,480,000 floats
    // total: 122,880,000 floats = 491.5 MB

    const int M = M_;
    const int gemm_grid = (M + 95) / 96;   // 5334

    // Layer 0
    gemm_xg<80><<<dim3(gemm_grid), dim3(256), 0, stream>>>(x, wih0, b0, xg, M);
    lstm_scan<<<dim3(B_), dim3(64), 0, stream>>>(xg, whh0, h0, T_);
    // Layer 1
    gemm_xg<40><<<dim3(gemm_grid), dim3(256), 0, stream>>>(h0, wih1, b1, xg, M);
    lstm_scan<<<dim3(B_), dim3(64), 0, stream>>>(xg, whh1, h1, T_);
    // FC
    fc_kernel<<<dim3(M / 256), dim3(256), 0, stream>>>(h1, fcw, fcb, out);
}

// Round 2
// 1965.922 us; speedup vs baseline: 1.4457x; 1.4457x over previous
//
#include <hip/hip_runtime.h>
#include <math.h>

// Problem constants
#define B_ 256
#define T_ 2000
#define I_ 80
#define H_ 20
#define G_ 80      // 4*H
#define M_ 512000  // B*T

// Fast activations: v_exp + v_rcp (approx rcp, ~1 ULP; threshold is 7.2e-3)
__device__ __forceinline__ float sigmoid_f(float x) {
    return __builtin_amdgcn_rcpf(1.0f + __expf(-x));
}
__device__ __forceinline__ float tanh_f(float x) {
    // 1 - 2/(exp(2x)+1): exactly saturating at +-1 for large |x|
    return fmaf(-2.0f, __builtin_amdgcn_rcpf(__expf(2.0f * x) + 1.0f), 1.0f);
}

// ---------------------------------------------------------------------------
// GEMM: XG[row][d*80 + j*4 + g] = sum_k X[row][k] * Wih[d][k][g*20+j] + B[d][g*20+j]
// NOTE the GATE-INTERLEAVED output column order (j*4+g): the scan kernel reads
// one float4 per hidden unit j = all 4 gate pre-activations. The permutation
// is free here (weight staging is a gather from global anyway).
// rows = B*T, K = 80 (layer0) or 40 (layer1), N = 160 (both dirs)
// tile: 96 rows x 160 cols, 8x8 micro-tile, K staged in chunks of 40.
// ---------------------------------------------------------------------------
template<int K>
__global__ __launch_bounds__(256) void gemm_xg(
    const float* __restrict__ X,     // (M, K)
    const float* __restrict__ Wih,   // (2, K, 80)
    const float* __restrict__ Bias,  // (2, 80)
    float* __restrict__ XG,          // (M, 160) permuted cols
    int M)
{
    constexpr int KC = 40;
    __shared__ float ws[KC][164];   // [k][col'], pad 160->164
    __shared__ float xs[KC][100];   // [k][row], pad 96->100
    __shared__ float bs[160];

    const int tid  = threadIdx.x;
    const int row0 = blockIdx.x * 96;
    const int tx = tid % 20;        // col group: cols 8*tx .. 8*tx+7
    const int ty = tid / 20;        // row group: rows 8*ty .. 8*ty+7 (ty<12 active)
    const bool run = (ty < 12);

    if (tid < 160) {
        int dd = (tid >= 80);
        int r = tid - 80 * dd;
        int j = r >> 2, g = r & 3;
        bs[tid] = Bias[dd * 80 + g * 20 + j];
    }

    int nrows = M - row0; if (nrows > 96) nrows = 96;

    float acc[8][8];
    bool first = true;

    for (int kc = 0; kc < K; kc += KC) {
        // stage weights chunk, gate-interleaved: col' = d*80 + j*4 + g
        for (int idx = tid; idx < KC * 160; idx += 256) {
            int i = idx / 160, cc = idx - 160 * i;
            int dd = (cc >= 80), r = cc - 80 * dd;
            int j = r >> 2, g = r & 3;
            ws[i][cc] = Wih[(dd * K + kc + i) * 80 + g * 20 + j];
        }
        // stage x chunk, transposed: xs[k][r] = X[row0+r][kc+k]
        for (int i4 = tid; i4 < (96 * KC) / 4; i4 += 256) {
            int r = i4 / 10;
            int kk = (i4 - 10 * r) * 4;
            float4 v = make_float4(0.f, 0.f, 0.f, 0.f);
            if (r < nrows)
                v = *(const float4*)(X + (long long)(row0 + r) * K + kc + kk);
            xs[kk][r] = v.x; xs[kk + 1][r] = v.y; xs[kk + 2][r] = v.z; xs[kk + 3][r] = v.w;
        }
        __syncthreads();

        if (first) {
            first = false;
            float bv[8];
            #pragma unroll
            for (int cc = 0; cc < 8; ++cc) bv[cc] = bs[tx * 8 + cc];
            #pragma unroll
            for (int r = 0; r < 8; ++r)
                #pragma unroll
                for (int cc = 0; cc < 8; ++cc) acc[r][cc] = bv[cc];
        }

        if (run) {
            #pragma unroll 4
            for (int k = 0; k < KC; ++k) {
                float a[8], bb[8];
                *(float4*)&a[0]  = *(const float4*)&xs[k][ty * 8];
                *(float4*)&a[4]  = *(const float4*)&xs[k][ty * 8 + 4];
                *(float4*)&bb[0] = *(const float4*)&ws[k][tx * 8];
                *(float4*)&bb[4] = *(const float4*)&ws[k][tx * 8 + 4];
                #pragma unroll
                for (int r = 0; r < 8; ++r)
                    #pragma unroll
                    for (int cc = 0; cc < 8; ++cc)
                        acc[r][cc] = fmaf(a[r], bb[cc], acc[r][cc]);
            }
        }
        __syncthreads();
    }

    if (run) {
        #pragma unroll
        for (int r = 0; r < 8; ++r) {
            int row = row0 + ty * 8 + r;
            if (row < M) {
                float* dst = XG + (long long)row * 160 + tx * 8;
                *(float4*)(dst)     = *(float4*)&acc[r][0];
                *(float4*)(dst + 4) = *(float4*)&acc[r][4];
            }
        }
    }
}

// ---------------------------------------------------------------------------
// LSTM scan v2: ONE (batch, direction) sequence per WAVE. 512 blocks x 64.
//  - lane j (j<20) owns hidden unit j: c_j + 80 recurrent weights in VGPRs
//  - h is wave-uniform -> broadcast via v_readlane into SGPRs (no LDS/shfl,
//    no per-broadcast VALU address math; FMA reads SGPR x VGPR)
//  - xg is gate-interleaved: lane j loads ONE float4 = 4 gate pre-activations
//  - 8-deep software prefetch pipeline (lookahead ~8 steps >> HBM latency)
// ---------------------------------------------------------------------------
__global__ __launch_bounds__(64) void lstm_scan(
    const float* __restrict__ xg,    // (B,T,2,20,4): ((b*T+t)*2+d)*80 + j*4+g
    const float* __restrict__ w_hh,  // (2, 20, 80)
    float* __restrict__ h_out,       // (B, T, 40): [b][t][d*20+j]
    int T)
{
    const int sid  = blockIdx.x;          // 0..511
    const int b    = sid >> 1;
    const int d    = sid & 1;
    const int lane = threadIdx.x & 63;
    const bool act = (lane < H_);
    const int jj   = act ? lane : 0;      // clamp for safe addressing

    // Recurrent weights: wr[g][k] = w_hh[d][k][g*20 + jj]
    float wr[4][20];
    const float* wbase = w_hh + d * (H_ * G_);
    #pragma unroll
    for (int k = 0; k < 20; ++k) {
        #pragma unroll
        for (int g = 0; g < 4; ++g)
            wr[g][k] = wbase[k * G_ + g * 20 + jj];
    }

    // Wave-uniform h, lives in SGPRs via readlane
    float sh[20];
    #pragma unroll
    for (int k = 0; k < 20; ++k) sh[k] = 0.f;
    float c = 0.f;

    const int t0    = d ? (T - 1) : 0;
    const int rstep = d ? -160 : 160;           // elements per t-step
    const float* pf = xg + ((long long)(b * T + t0) * 2 + d) * 80 + 4 * jj;

    float* hout = h_out + (long long)(b * T + t0) * 40 + d * 20 + lane;
    const int hstep = d ? -40 : 40;

    constexpr int PF = 8;
    float4 px[PF];
    #pragma unroll
    for (int s = 0; s < PF; ++s) { px[s] = *(const float4*)pf; pf += rstep; }
    // pf now points at step t0 + PF*rstep

    for (int tb = 0; tb < T; tb += PF) {
        #pragma unroll
        for (int s = 0; s < PF; ++s) {
            const int t = tb + s;
            const float4 v = px[s];   // (xi, xf, xg, xo) for unit jj

            // prefetch t+PF into the slot just consumed
            if (t + PF < T) { px[s] = *(const float4*)pf; pf += rstep; }

            // 4 accumulators per gate: chain depth 5 + 2-deep reduction
            float a0[4], a1[4], a2[4], a3[4];
            a0[0]=v.x; a0[1]=v.y; a0[2]=v.z; a0[3]=v.w;
            #pragma unroll
            for (int g = 0; g < 4; ++g) { a1[g]=0.f; a2[g]=0.f; a3[g]=0.f; }
            #pragma unroll
            for (int k = 0; k < 20; k += 4) {
                #pragma unroll
                for (int g = 0; g < 4; ++g) {
                    a0[g] = fmaf(sh[k],     wr[g][k],     a0[g]);
                    a1[g] = fmaf(sh[k + 1], wr[g][k + 1], a1[g]);
                    a2[g] = fmaf(sh[k + 2], wr[g][k + 2], a2[g]);
                    a3[g] = fmaf(sh[k + 3], wr[g][k + 3], a3[g]);
                }
            }
            const float gi = sigmoid_f((a0[0] + a1[0]) + (a2[0] + a3[0]));
            const float gf = sigmoid_f((a0[1] + a1[1]) + (a2[1] + a3[1]));
            const float gg = tanh_f   ((a0[2] + a1[2]) + (a2[2] + a3[2]));
            const float go = sigmoid_f((a0[3] + a1[3]) + (a2[3] + a3[3]));

            c = fmaf(gf, c, gi * gg);
            const float hj = go * tanh_f(c);

            if (act) *hout = hj;
            hout += hstep;

            // broadcast h into wave-uniform (SGPR) copies
            #pragma unroll
            for (int k = 0; k < 20; ++k)
                sh[k] = __uint_as_float(__builtin_amdgcn_readlane(__float_as_uint(hj), k));
        }
    }
}

// ---------------------------------------------------------------------------
// FC: out[row] = dot(h1[row][0:40], fc_w) + fc_b.  256 rows per block.
// ---------------------------------------------------------------------------
__global__ __launch_bounds__(256) void fc_kernel(
    const float* __restrict__ H1,   // (M, 40)
    const float* __restrict__ Wf,   // (40,)
    const float* __restrict__ Bf,   // (1,)
    float* __restrict__ Out)        // (M,)
{
    __shared__ float ls[256 * 41];
    __shared__ float wl[40];
    const int tid = threadIdx.x;
    const long long row0 = (long long)blockIdx.x * 256;
    const float* src = H1 + row0 * 40;

    #pragma unroll
    for (int it = 0; it < 10; ++it) {
        int i4 = tid + it * 256;            // 0..2559
        float4 v = *(const float4*)(src + (long long)i4 * 4);
        int flat = i4 * 4;
        int r = flat / 40, jc = flat - 40 * r;  // 40%4==0: never straddles rows
        float* dp = &ls[r * 41 + jc];
        dp[0] = v.x; dp[1] = v.y; dp[2] = v.z; dp[3] = v.w;
    }
    if (tid < 40) wl[tid] = Wf[tid];
    __syncthreads();

    float acc = Bf[0];
    #pragma unroll
    for (int jc = 0; jc < 40; ++jc)
        acc = fmaf(ls[tid * 41 + jc], wl[jc], acc);
    Out[row0 + tid] = acc;
}

// ---------------------------------------------------------------------------
extern "C" void kernel_launch(void* const* d_in, const int* in_sizes, int n_in,
                              void* d_out, int out_size, void* d_ws, size_t ws_size,
                              hipStream_t stream) {
    const float* x     = (const float*)d_in[0];
    const float* wih0  = (const float*)d_in[1];
    const float* whh0  = (const float*)d_in[2];
    const float* b0    = (const float*)d_in[3];
    const float* wih1  = (const float*)d_in[4];
    const float* whh1  = (const float*)d_in[5];
    const float* b1    = (const float*)d_in[6];
    const float* fcw   = (const float*)d_in[7];
    const float* fcb   = (const float*)d_in[8];
    float* out = (float*)d_out;

    float* ws = (float*)d_ws;
    float* xg = ws;                        // B*T*2*80 = 81,920,000 floats
    float* h0 = ws + 81920000LL;           // B*T*40   = 20,480,000 floats
    float* h1 = ws + 102400000LL;          // B*T*40   = 20,480,000 floats
    // total: 122,880,000 floats = 491.5 MB

    const int M = M_;
    const int gemm_grid = (M + 95) / 96;   // 5334

    // Layer 0
    gemm_xg<80><<<dim3(gemm_grid), dim3(256), 0, stream>>>(x, wih0, b0, xg, M);
    lstm_scan<<<dim3(2 * B_), dim3(64), 0, stream>>>(xg, whh0, h0, T_);
    // Layer 1
    gemm_xg<40><<<dim3(gemm_grid), dim3(256), 0, stream>>>(h0, wih1, b1, xg, M);
    lstm_scan<<<dim3(2 * B_), dim3(64), 0, stream>>>(xg, whh1, h1, T_);
    // FC
    fc_kernel<<<dim3(M / 256), dim3(256), 0, stream>>>(h1, fcw, fcb, out);
}